// Round 15
// baseline (798.452 us; speedup 1.0000x reference)
//
#include <hip/hip_runtime.h>
#include <hip/hip_bf16.h>

// Problem constants
#define NB    2048   // batch
#define SS    200    // seq len
#define NTIL  13     // s-tiles of 16 (208 padded)
#define DSEQ  256
#define DITEM 64
#define AA    128    // attn dim (H=1, HD=128)

typedef __bf16 bf16x8 __attribute__((ext_vector_type(8)));
typedef __bf16 bf16x4 __attribute__((ext_vector_type(4)));
typedef float  f32x4  __attribute__((ext_vector_type(4)));

__device__ __forceinline__ float prelu_f(float x, float a) { return x >= 0.f ? x : a * x; }

// 16-lane sum via DPP row_ror — VALU pipe only; result valid in all 16 lanes.
#define ROR_F(x, n) __int_as_float(__builtin_amdgcn_update_dpp(0, __float_as_int(x), 0x120 + (n), 0xf, 0xf, true))
__device__ __forceinline__ float row_sum16(float x) {
    x += ROR_F(x, 1); x += ROR_F(x, 2); x += ROR_F(x, 4); x += ROR_F(x, 8);
    return x;
}

// ---------------- prep_w: W_k|W_v -> bf16 [256 rows][256], LINEAR (no swizzle)
__global__ void prep_w(const float* __restrict__ Wk, const float* __restrict__ Wv,
                       __hip_bfloat16* __restrict__ Wb) {
    int idx = blockIdx.x * 256 + threadIdx.x;   // 256 blocks -> 65536
    int a = idx >> 8, d = idx & 255;
    float v = (a < 128) ? Wk[a * 256 + d] : Wv[(a - 128) * 256 + d];
    Wb[idx] = __float2bfloat16(v);
}

// ---------------- prep_u: u[b][a] = Wker @ prelu(Wq @ temb[b])
__global__ __launch_bounds__(128) void prep_u(
    const float* __restrict__ temb, const float* __restrict__ Wq,
    const float* __restrict__ Wker, const float* __restrict__ prelu_a,
    float* __restrict__ u) {
    __shared__ float tl[DITEM];
    __shared__ float ql[AA];
    const int b = blockIdx.x, tid = threadIdx.x;
    const float pa = *prelu_a;
    if (tid < DITEM) tl[tid] = temb[(size_t)b * DITEM + tid];
    __syncthreads();
    float acc = 0.f;
    #pragma unroll
    for (int d4 = 0; d4 < 16; d4++) {
        f32x4 tv = *reinterpret_cast<const f32x4*>(&tl[d4 * 4]);
        f32x4 wv = *reinterpret_cast<const f32x4*>(Wq + (size_t)tid * DITEM + d4 * 4);
        acc += wv[0]*tv[0] + wv[1]*tv[1] + wv[2]*tv[2] + wv[3]*tv[3];
    }
    ql[tid] = prelu_f(acc, pa);
    __syncthreads();
    acc = 0.f;
    #pragma unroll
    for (int c4 = 0; c4 < 32; c4++) {
        f32x4 qv = *reinterpret_cast<const f32x4*>(&ql[c4 * 4]);
        f32x4 wv = *reinterpret_cast<const f32x4*>(Wker + (size_t)tid * AA + c4 * 4);
        acc += wv[0]*qv[0] + wv[1]*qv[1] + wv[2]*qv[2] + wv[3]*qv[3];
    }
    u[(size_t)b * AA + tid] = acc;
}

// half-tile X load: st[8h..8h+7]
#define ISSUE_H(tt, h)                                                          \
    {                                                                           \
        int r_ = (tt) * 16 + c; r_ = r_ < SS ? r_ : SS - 1;                     \
        const float* xp_ = X + ((size_t)b * SS + r_) * DSEQ + rg * 8 + (h) * 128; \
        _Pragma("unroll")                                                       \
        for (int k_ = 0; k_ < 4; k_++) {                                        \
            st[(h) * 8 + 2 * k_]     = *reinterpret_cast<const f32x4*>(xp_ + k_ * 32);     \
            st[(h) * 8 + 2 * k_ + 1] = *reinterpret_cast<const f32x4*>(xp_ + k_ * 32 + 4); \
        }                                                                       \
    }

// 4 col-groups of K/V MFMA + score partial + V store
#define CTBLOCK(ct0)                                                            \
    _Pragma("unroll")                                                           \
    for (int ct = (ct0); ct < (ct0) + 4; ct++) {                                \
        const char* wkp = Wbb + (size_t)(16 * ct + c) * 512;                    \
        const char* wvp = wkp + 65536;                                          \
        f32x4 aK = {0.f,0.f,0.f,0.f}, aV = {0.f,0.f,0.f,0.f};                   \
        _Pragma("unroll")                                                       \
        for (int k = 0; k < 8; k++) {                                           \
            const int o = k * 64 + rg * 16;                                     \
            aK = __builtin_amdgcn_mfma_f32_16x16x32_bf16(af[k], *reinterpret_cast<const bf16x8*>(wkp + o), aK, 0, 0, 0); \
            aV = __builtin_amdgcn_mfma_f32_16x16x32_bf16(af[k], *reinterpret_cast<const bf16x8*>(wvp + o), aV, 0, 0, 0); \
        }                                                                       \
        _Pragma("unroll")                                                       \
        for (int i = 0; i < 4; i++) pr[i] += prelu_f(aK[i], pa) * uu[ct];       \
        bf16x4 vv;                                                              \
        _Pragma("unroll")                                                       \
        for (int i = 0; i < 4; i++) vv[i] = (__bf16)prelu_f(aV[i], pa);         \
        *reinterpret_cast<bf16x4*>(vout + ct * 512) = vv;                       \
    }

// ---------------- proj: one WAVE per batch row; NO LDS, NO barriers.
// Streams X from HBM, W from L2; writes raw scores (f32) + prelu'd V (bf16, packed).
__global__ __launch_bounds__(512) void proj(
    const float* __restrict__ X,            // [2048,200,256]
    const __hip_bfloat16* __restrict__ Wb,  // ws: bf16 weights [256][256] linear
    const float* __restrict__ u,            // ws: [2048][128]
    const float* __restrict__ prelu_a,
    float* __restrict__ scores,             // ws: [2048][208] f32 raw
    char* __restrict__ Vbuf)                // ws: [2048][13][8ct][64lane][4] bf16
{
    const int tid  = threadIdx.x;
    const int w    = tid >> 6;
    const int lane = tid & 63;
    const int c    = lane & 15;       // s within tile (A-row) / a within group (D-col)
    const int rg   = lane >> 4;       // k-group / D-row-group
    const int b    = blockIdx.x * 8 + w;
    const float pa = *prelu_a;
    const char* Wbb = (const char*)Wb;

    float uu[8];
    #pragma unroll
    for (int ct = 0; ct < 8; ct++) uu[ct] = u[(size_t)b * AA + ct * 16 + c];

    f32x4 st[16];
    bf16x8 af[8];
    ISSUE_H(0, 0); ISSUE_H(0, 1);

    float* scoreb = scores + (size_t)b * 208;

    for (int t = 0; t < NTIL; t++) {
        // convert st -> af (waits on loads; st dies progressively)
        #pragma unroll
        for (int k = 0; k < 8; k++) {
            f32x4 lo = st[2 * k], hi = st[2 * k + 1];
            bf16x8 v;
            v[0]=(__bf16)lo[0]; v[1]=(__bf16)lo[1]; v[2]=(__bf16)lo[2]; v[3]=(__bf16)lo[3];
            v[4]=(__bf16)hi[0]; v[5]=(__bf16)hi[1]; v[6]=(__bf16)hi[2]; v[7]=(__bf16)hi[3];
            af[k] = v;
        }
        // prefetch next tile, half 0 (covered by first 4 col-groups)
        if (t + 1 < NTIL) ISSUE_H(t + 1, 0);

        f32x4 pr = {0.f, 0.f, 0.f, 0.f};
        char* vout = Vbuf + ((size_t)b * NTIL + t) * 4096 + lane * 8;

        CTBLOCK(0);
        if (t + 1 < NTIL) ISSUE_H(t + 1, 1);
        CTBLOCK(4);

        #pragma unroll
        for (int i = 0; i < 4; i++) pr[i] = row_sum16(pr[i]);
        if (c == 0) *reinterpret_cast<f32x4*>(scoreb + t * 16 + rg * 4) = pr;
    }
}

// ---------------- attn_ffn: one 256-thread block per batch row
__global__ __launch_bounds__(256) void attn_ffn(
    const float* __restrict__ scores,  // ws raw
    const int*   __restrict__ maskp,
    const char*  __restrict__ Vbuf,
    const float* __restrict__ ffnW,    // [256,128]
    const float* __restrict__ ffnb,
    const float* __restrict__ prelu_a,
    float* __restrict__ out)
{
    __shared__ float ebuf[208];
    __shared__ float ovec[AA];
    __shared__ float red[256];
    __shared__ float wr1[4], wr2[4];

    const int b = blockIdx.x, tid = threadIdx.x;
    const int w = tid >> 6, lane = tid & 63;
    const float pa = *prelu_a;
    const float inv_scale = 0.08838834764831845f;  // 1/sqrt(128)

    float sc = -3e38f;
    if (tid < 208) {
        float s = scores[(size_t)b * 208 + tid] * inv_scale;
        int mk = (tid < SS) ? maskp[(size_t)b * SS + tid] : 1;
        sc = mk ? -1e9f : s;
    }
    // block max
    float v = sc;
    #pragma unroll
    for (int o = 1; o < 64; o <<= 1) v = fmaxf(v, __shfl_xor(v, o, 64));
    if (lane == 0) wr1[w] = v;
    __syncthreads();
    const float m = fmaxf(fmaxf(wr1[0], wr1[1]), fmaxf(wr1[2], wr1[3]));
    float e = (tid < 208) ? __expf(sc - m) : 0.f;
    if (tid < 208) ebuf[tid] = e;
    float sv = e;
    #pragma unroll
    for (int o = 1; o < 64; o <<= 1) sv += __shfl_xor(sv, o, 64);
    if (lane == 0) wr2[w] = sv;
    __syncthreads();
    const float l = wr2[0] + wr2[1] + wr2[2] + wr2[3];
    const float invl = 1.0f / l;

    // attn output
    if (tid < SS)
        out[(size_t)NB * DSEQ + (size_t)b * SS + tid] = ebuf[tid] * invl;

    // O[a] = sum_s e_s * V[s,a]; threads split s-range in halves
    const int a = tid & 127, h = tid >> 7;
    const int t0 = h ? 7 : 0, t1 = h ? 13 : 7;
    const char* vbase = Vbuf + (size_t)b * NTIL * 4096 + (a >> 4) * 512 + (a & 15) * 8;
    float acc = 0.f;
    for (int t = t0; t < t1; t++) {
        #pragma unroll
        for (int rg = 0; rg < 4; rg++) {
            bf16x4 vv = *reinterpret_cast<const bf16x4*>(vbase + (size_t)t * 4096 + rg * 128);
            const int s = t * 16 + rg * 4;
            acc += ebuf[s]     * (float)vv[0] + ebuf[s + 1] * (float)vv[1]
                 + ebuf[s + 2] * (float)vv[2] + ebuf[s + 3] * (float)vv[3];
        }
    }
    red[tid] = acc;
    __syncthreads();
    if (tid < AA) ovec[tid] = (red[tid] + red[tid + 128]) * invl;
    __syncthreads();

    // FFN
    float facc = ffnb[tid];
    #pragma unroll 8
    for (int a4 = 0; a4 < 32; a4++) {
        f32x4 ov = *reinterpret_cast<const f32x4*>(&ovec[a4 * 4]);
        f32x4 wv = *reinterpret_cast<const f32x4*>(ffnW + (size_t)tid * AA + a4 * 4);
        facc += wv[0]*ov[0] + wv[1]*ov[1] + wv[2]*ov[2] + wv[3]*ov[3];
    }
    out[(size_t)b * DSEQ + tid] = prelu_f(facc, pa);
}

extern "C" void kernel_launch(void* const* d_in, const int* in_sizes, int n_in,
                              void* d_out, int out_size, void* d_ws, size_t ws_size,
                              hipStream_t stream) {
    const float* X    = (const float*)d_in[0];
    const int*   mask = (const int*)  d_in[1];
    const float* temb = (const float*)d_in[2];
    const float* Wq   = (const float*)d_in[3];
    const float* Wk   = (const float*)d_in[4];
    const float* Wv   = (const float*)d_in[5];
    const float* Wker = (const float*)d_in[6];
    const float* ffnW = (const float*)d_in[7];
    const float* ffnb = (const float*)d_in[8];
    const float* pa   = (const float*)d_in[9];
    float* out = (float*)d_out;

    // ws layout (4K-aligned): Wb 128KB | u 1MB | Vbuf 104MB | scores 1.7MB
    char* ws = (char*)d_ws;
    __hip_bfloat16* Wb = (__hip_bfloat16*)ws;
    float* u      = (float*)(ws + 131072);
    char*  Vbuf   = ws + 131072 + 1048576;
    float* scores = (float*)(ws + 131072 + 1048576 + (size_t)NB * NTIL * 4096);

    prep_w<<<256, 256, 0, stream>>>(Wk, Wv, Wb);
    prep_u<<<NB, 128, 0, stream>>>(temb, Wq, Wker, pa, u);
    proj<<<NB / 8, 512, 0, stream>>>(X, Wb, u, pa, scores, Vbuf);
    attn_ffn<<<NB, 256, 0, stream>>>(scores, mask, Vbuf, ffnW, ffnb, pa, out);
}

// Round 16
// 172.359 us; speedup vs baseline: 4.6325x; 4.6325x over previous
//
#include <hip/hip_runtime.h>
#include <hip/hip_bf16.h>

// Problem constants
#define NB    2048   // batch
#define SS    200    // seq len
#define NTIL  13     // s-tiles of 16 (208 padded)
#define DSEQ  256
#define DITEM 64
#define AA    128    // attn dim (H=1, HD=128)

typedef __bf16 bf16x8 __attribute__((ext_vector_type(8)));
typedef float  f32x4  __attribute__((ext_vector_type(4)));

__device__ __forceinline__ float prelu_f(float x, float a) { return x >= 0.f ? x : a * x; }

// 16-lane reduce via DPP row_ror — VALU pipe only; result valid in all 16 lanes.
#define ROR_F(x, n) __int_as_float(__builtin_amdgcn_update_dpp(0, __float_as_int(x), 0x120 + (n), 0xf, 0xf, true))
__device__ __forceinline__ float row_sum16(float x) {
    x += ROR_F(x, 1); x += ROR_F(x, 2); x += ROR_F(x, 4); x += ROR_F(x, 8);
    return x;
}
__device__ __forceinline__ float row_max16(float x) {
    x = fmaxf(x, ROR_F(x, 1)); x = fmaxf(x, ROR_F(x, 2));
    x = fmaxf(x, ROR_F(x, 4)); x = fmaxf(x, ROR_F(x, 8));
    return x;
}

// ---------------- prep: W_k|W_v -> bf16 [256 rows][512B], XOR-swizzled within rows
__global__ void prep_kernel(const float* __restrict__ Wk, const float* __restrict__ Wv,
                            __hip_bfloat16* __restrict__ Wb) {
    int idx = blockIdx.x * 256 + threadIdx.x;   // 256 blocks -> 65536
    int a = idx >> 8, d = idx & 255;
    float v = (a < 128) ? Wk[a * 256 + d] : Wv[(a - 128) * 256 + d];
    int boff = (d * 2) ^ ((a & 7) << 4);
    Wb[a * 256 + (boff >> 1)] = __float2bfloat16(v);
}

// per-thread staging for stream s
#define ISSUE(tt, s)                                                            \
    {                                                                           \
        int r_ = (tt) * 16 + srow; r_ = r_ < SS ? r_ : SS - 1;                  \
        const float* xp_ = Xp##s + (size_t)r_ * DSEQ + chunk * 8;               \
        stlo##s = *reinterpret_cast<const f32x4*>(xp_);                         \
        sthi##s = *reinterpret_cast<const f32x4*>(xp_ + 4);                     \
    }

#define STAGE(tt, s)                                                            \
    {                                                                           \
        bf16x8 v_;                                                              \
        v_[0] = (__bf16)stlo##s[0]; v_[1] = (__bf16)stlo##s[1];                 \
        v_[2] = (__bf16)stlo##s[2]; v_[3] = (__bf16)stlo##s[3];                 \
        v_[4] = (__bf16)sthi##s[0]; v_[5] = (__bf16)sthi##s[1];                 \
        v_[6] = (__bf16)sthi##s[2]; v_[7] = (__bf16)sthi##s[3];                 \
        *reinterpret_cast<bf16x8*>(xb##s + ((tt) & 3) * 8192 + wr_off) = v_;    \
    }

// deferred online-softmax + V-fold of tile `tp`, stream s, V-acc register AVP
#define SMFOLD(tp, s, AVP)                                                      \
    {                                                                           \
        const int q_ = (tp) & 3;                                                \
        const int s0_ = (tp) * 16;                                              \
        f32x4 r0_ = *reinterpret_cast<const f32x4*>(&sp##s[q_][c][0]);          \
        f32x4 r1_ = *reinterpret_cast<const f32x4*>(&sp##s[q_][c][4]);          \
        float sc_ = (r0_[0]+r0_[1]+r0_[2]+r0_[3]+r1_[0]+r1_[1]+r1_[2]+r1_[3]) * inv_scale; \
        sc_ = mask##s[s0_ + c] ? -1e9f : sc_;                                   \
        if (tid < 16) score_buf##s[s0_ + tid] = sc_;                            \
        float tmax_ = row_max16(sc_);                                           \
        float nm_ = fmaxf(m##s, tmax_);                                         \
        float fs_ = __expf(m##s - nm_);                                         \
        float e_  = __expf(sc_ - nm_);                                          \
        float ls_ = row_sum16(e_);                                              \
        l##s = l##s * fs_ + ls_; m##s = nm_;                                    \
        oacc##s *= fs_;                                                         \
        _Pragma("unroll")                                                       \
        for (int i_ = 0; i_ < 4; i_++) {                                        \
            float ew_ = __shfl(e_, (lane & 48) | (rg * 4 + i_), 64);            \
            oacc##s += ew_ * prelu_f(AVP[i_], pa);                              \
        }                                                                       \
    }

// compute tile tt for both streams; K and V weight frags streamed from L2
#define COMPUTE(tt, A0, A1)                                                     \
    {                                                                           \
        const char* rb0 = xb0 + ((tt) & 3) * 8192 + c * 512;                    \
        const char* rb1 = xb1 + ((tt) & 3) * 8192 + c * 512;                    \
        f32x4 aK0 = {0.f,0.f,0.f,0.f}, aV0 = {0.f,0.f,0.f,0.f};                 \
        f32x4 aK1 = {0.f,0.f,0.f,0.f}, aV1 = {0.f,0.f,0.f,0.f};                 \
        _Pragma("unroll")                                                       \
        for (int k = 0; k < 8; k++) {                                           \
            const int o = (k * 64 + rg * 16) ^ rswz;                            \
            bf16x8 bk  = *reinterpret_cast<const bf16x8*>(kb + o);              \
            bf16x8 bv  = *reinterpret_cast<const bf16x8*>(vb + o);              \
            bf16x8 af0 = *reinterpret_cast<const bf16x8*>(rb0 + o);             \
            bf16x8 af1 = *reinterpret_cast<const bf16x8*>(rb1 + o);             \
            aK0 = __builtin_amdgcn_mfma_f32_16x16x32_bf16(af0, bk, aK0, 0, 0, 0); \
            aK1 = __builtin_amdgcn_mfma_f32_16x16x32_bf16(af1, bk, aK1, 0, 0, 0); \
            aV0 = __builtin_amdgcn_mfma_f32_16x16x32_bf16(af0, bv, aV0, 0, 0, 0); \
            aV1 = __builtin_amdgcn_mfma_f32_16x16x32_bf16(af1, bv, aV1, 0, 0, 0); \
        }                                                                       \
        float pr0[4], pr1[4];                                                   \
        _Pragma("unroll")                                                       \
        for (int i = 0; i < 4; i++) {                                           \
            pr0[i] = row_sum16(prelu_f(aK0[i], pa) * uwK0);                     \
            pr1[i] = row_sum16(prelu_f(aK1[i], pa) * uwK1);                     \
        }                                                                       \
        if (c == 0) {                                                           \
            _Pragma("unroll")                                                   \
            for (int i = 0; i < 4; i++) {                                       \
                sp0[(tt) & 3][rg * 4 + i][w] = pr0[i];                          \
                sp1[(tt) & 3][rg * 4 + i][w] = pr1[i];                          \
            }                                                                   \
        }                                                                       \
        A0 = aV0; A1 = aV1;                                                     \
    }

// ---------------- main: one BLOCK (8 waves) per TWO batch rows, 2-tile epochs.
// 4-deep LDS tile buffers; one barrier per 2 tiles; K and V streamed from L2.
__global__ __launch_bounds__(512)
void pool_main(
    const float* __restrict__ X,      // [2048,200,256]
    const int*   __restrict__ maskp,  // [2048,200] 1 = pad
    const float* __restrict__ temb,   // [2048,64]
    const float* __restrict__ Wq,     // [128,64]
    const float* __restrict__ Wker,   // [128,128]
    const float* __restrict__ ffnW,   // [256,128]
    const float* __restrict__ ffnb,   // [256]
    const float* __restrict__ prelu_a,
    const __hip_bfloat16* __restrict__ Wb,  // ws: swizzled bf16 weights [256][256]
    float* __restrict__ out)          // [2048*256] ffn, then [2048*200] attn
{
    __shared__ __hip_bfloat16 Xt0[4][16][256];   // 32 KB
    __shared__ __hip_bfloat16 Xt1[4][16][256];   // 32 KB
    __shared__ float sp0[4][16][8], sp1[4][16][8];
    __shared__ float score_buf0[208], score_buf1[208];
    __shared__ float out_vec0[AA], out_vec1[AA];
    __shared__ float tq0[DITEM], tq1[DITEM];
    __shared__ float Qv0[AA], Qv1[AA];
    __shared__ float uv0[AA], uv1[AA];
    __shared__ int   mask0[208], mask1[208];

    const int tid  = threadIdx.x;
    const int w    = tid >> 6;        // wave 0..7
    const int lane = tid & 63;
    const int c    = lane & 15;
    const int rg   = lane >> 4;
    const int b0   = blockIdx.x * 2;
    const int b1   = b0 + 1;
    const float pa = *prelu_a;
    const float inv_scale = 0.08838834764831845f;  // 1/sqrt(128)

    const int srow  = tid >> 5;       // staging row 0..15
    const int chunk = tid & 31;       // 32B chunk in row
    const int wr_off = srow * 512 + ((chunk * 16) ^ ((srow & 7) << 4));
    char* xb0 = (char*)&Xt0[0][0][0];
    char* xb1 = (char*)&Xt1[0][0][0];
    const int rswz = (c & 7) << 4;
    const float* Xp0 = X + (size_t)b0 * SS * DSEQ;
    const float* Xp1 = X + (size_t)b1 * SS * DSEQ;

    // K/V weight fragment base pointers (L2-resident, shared by all blocks)
    const char* kb = (const char*)Wb + (size_t)(16 * w + c) * 512;
    const char* vb = kb + 65536;

    // ---- small staging (both streams in parallel) + X tile-0 issue
    if (tid < DITEM)                     tq0[tid]       = temb[(size_t)b0 * DITEM + tid];
    else if (tid < 2 * DITEM)            tq1[tid - 64]  = temb[(size_t)b1 * DITEM + tid - 64];
    if (tid < 208)                       mask0[tid]        = (tid < SS) ? maskp[(size_t)b0 * SS + tid] : 1;
    else if (tid >= 256 && tid < 464)    mask1[tid - 256]  = (tid - 256 < SS) ? maskp[(size_t)b1 * SS + tid - 256] : 1;
    f32x4 stlo0, sthi0, stlo1, sthi1;
    ISSUE(0, 0); ISSUE(0, 1);
    __syncthreads();

    // ---- Q for both streams (threads 0..127 -> b0, 128..255 -> b1)
    if (tid < 256) {
        const int o = tid & 127;
        const float* tqp = (tid < 128) ? tq0 : tq1;
        float acc = 0.f;
        #pragma unroll
        for (int d4 = 0; d4 < 16; d4++) {
            f32x4 tv = *reinterpret_cast<const f32x4*>(&tqp[d4 * 4]);
            f32x4 wq4 = *reinterpret_cast<const f32x4*>(Wq + (size_t)o * DITEM + d4 * 4);
            acc += wq4[0]*tv[0] + wq4[1]*tv[1] + wq4[2]*tv[2] + wq4[3]*tv[3];
        }
        if (tid < 128) Qv0[o] = prelu_f(acc, pa); else Qv1[o] = prelu_f(acc, pa);
    }
    __syncthreads();

    // ---- u for both streams
    if (tid < 256) {
        const int o = tid & 127;
        const float* qp = (tid < 128) ? Qv0 : Qv1;
        float acc = 0.f;
        #pragma unroll
        for (int d4 = 0; d4 < 32; d4++) {
            f32x4 qv = *reinterpret_cast<const f32x4*>(&qp[d4 * 4]);
            f32x4 wv4 = *reinterpret_cast<const f32x4*>(Wker + (size_t)o * AA + d4 * 4);
            acc += wv4[0]*qv[0] + wv4[1]*qv[1] + wv4[2]*qv[2] + wv4[3]*qv[3];
        }
        if (tid < 128) uv0[o] = acc; else uv1[o] = acc;
    }
    __syncthreads();
    const float uwK0 = uv0[16 * w + c];
    const float uwK1 = uv1[16 * w + c];

    // ---- prologue: tiles 0,1 staged
    STAGE(0, 0); STAGE(0, 1);
    ISSUE(1, 0); ISSUE(1, 1);
    STAGE(1, 0); STAGE(1, 1);
    __syncthreads();

    // ---- main loop: 2-tile epochs, 1 barrier per epoch
    float m0 = -INFINITY, l0 = 0.f, oacc0 = 0.f;
    float m1 = -INFINITY, l1 = 0.f, oacc1 = 0.f;
    f32x4 aVpA0 = {0.f,0.f,0.f,0.f}, aVpA1 = {0.f,0.f,0.f,0.f};
    f32x4 aVpB0 = {0.f,0.f,0.f,0.f}, aVpB1 = {0.f,0.f,0.f,0.f};

    for (int t = 0; t < NTIL - 1; t += 2) {      // t = 0,2,...,10 -> tiles t, t+1
        if (t + 2 < NTIL) { ISSUE(t + 2, 0); ISSUE(t + 2, 1); }

        if (t > 0) {
            SMFOLD(t - 2, 0, aVpA0); SMFOLD(t - 2, 1, aVpA1);
            SMFOLD(t - 1, 0, aVpB0); SMFOLD(t - 1, 1, aVpB1);
        }

        COMPUTE(t, aVpA0, aVpA1);

        if (t + 2 < NTIL) {
            STAGE(t + 2, 0); STAGE(t + 2, 1);
            if (t + 3 < NTIL) { ISSUE(t + 3, 0); ISSUE(t + 3, 1); }
        }

        COMPUTE(t + 1, aVpB0, aVpB1);

        if (t + 3 < NTIL) { STAGE(t + 3, 0); STAGE(t + 3, 1); }
        __syncthreads();
    }

    // ---- epilogue: folds for tiles 10,11; compute tile 12; final fold
    SMFOLD(NTIL - 3, 0, aVpA0); SMFOLD(NTIL - 3, 1, aVpA1);
    SMFOLD(NTIL - 2, 0, aVpB0); SMFOLD(NTIL - 2, 1, aVpB1);
    COMPUTE(NTIL - 1, aVpA0, aVpA1);
    __syncthreads();
    SMFOLD(NTIL - 1, 0, aVpA0); SMFOLD(NTIL - 1, 1, aVpA1);

    oacc0 += __shfl_xor(oacc0, 16, 64); oacc0 += __shfl_xor(oacc0, 32, 64);
    oacc1 += __shfl_xor(oacc1, 16, 64); oacc1 += __shfl_xor(oacc1, 32, 64);
    const float invl0 = 1.0f / l0, invl1 = 1.0f / l1;
    if (lane < 16) {
        out_vec0[16 * w + lane] = oacc0 * invl0;
        out_vec1[16 * w + lane] = oacc1 * invl1;
    }
    __syncthreads();

    // attn outputs
    if (tid < SS)
        out[(size_t)NB * DSEQ + (size_t)b0 * SS + tid] = __expf(score_buf0[tid] - m0) * invl0;
    else if (tid >= 256 && tid < 256 + SS)
        out[(size_t)NB * DSEQ + (size_t)b1 * SS + (tid - 256)] = __expf(score_buf1[tid - 256] - m1) * invl1;

    // FFN: threads 0..255 -> b0, 256..511 -> b1
    {
        const int o = tid & 255;
        const float* ovp = (tid < 256) ? out_vec0 : out_vec1;
        const int bo = (tid < 256) ? b0 : b1;
        float acc = ffnb[o];
        #pragma unroll 8
        for (int a4 = 0; a4 < 32; a4++) {
            f32x4 ov = *reinterpret_cast<const f32x4*>(&ovp[a4 * 4]);
            f32x4 wv4 = *reinterpret_cast<const f32x4*>(ffnW + (size_t)o * AA + a4 * 4);
            acc += wv4[0]*ov[0] + wv4[1]*ov[1] + wv4[2]*ov[2] + wv4[3]*ov[3];
        }
        out[(size_t)bo * DSEQ + o] = prelu_f(acc, pa);
    }
}

extern "C" void kernel_launch(void* const* d_in, const int* in_sizes, int n_in,
                              void* d_out, int out_size, void* d_ws, size_t ws_size,
                              hipStream_t stream) {
    const float* X    = (const float*)d_in[0];
    const int*   mask = (const int*)  d_in[1];
    const float* temb = (const float*)d_in[2];
    const float* Wq   = (const float*)d_in[3];
    const float* Wk   = (const float*)d_in[4];
    const float* Wv   = (const float*)d_in[5];
    const float* Wker = (const float*)d_in[6];
    const float* ffnW = (const float*)d_in[7];
    const float* ffnb = (const float*)d_in[8];
    const float* pa   = (const float*)d_in[9];
    float* out = (float*)d_out;

    __hip_bfloat16* Wb = (__hip_bfloat16*)d_ws;

    prep_kernel<<<256, 256, 0, stream>>>(Wk, Wv, Wb);
    pool_main<<<NB / 2, 512, 0, stream>>>(X, mask, temb, Wq, Wker, ffnW, ffnb, pa, Wb, out);
}